// Round 1
// baseline (13483.115 us; speedup 1.0000x reference)
//
#include <hip/hip_runtime.h>
#include <cstdint>

// LSTM: B=1024, T=336, I=64, H=256, gates 4H=1024, K = I+H = 320.
// 32 batch-groups x 8 member-WGs = 256 WGs (1/CU), persistent over all T.
// Weights live in VGPRs as MFMA A-fragments; h exchanged via global + flags.

#define B_TOT   1024
#define T_STEPS 336
#define I_DIM   64
#define H_DIM   256
#define K_DIM   320
#define NGROUP  32
#define NMEM    8
#define BATCH_G 32
#define ROWS_WG 128
#define VSTRIDE 328   // K=320 padded (ushorts)
#define GSTRIDE 34    // 32 batch padded (floats)
#define OUT_HALF 262144  // 1024*256

typedef __attribute__((ext_vector_type(8))) __bf16 bf16x8;
typedef __attribute__((ext_vector_type(8))) unsigned short ushort8_t;
typedef __attribute__((ext_vector_type(4))) float f32x4;

__device__ inline unsigned short f2bf(float f) {
  unsigned u = __builtin_bit_cast(unsigned, f);
  return (unsigned short)((u + 0x7fffu + ((u >> 16) & 1u)) >> 16);
}
__device__ inline float sigf(float x) { return 1.f / (1.f + __expf(-x)); }
__device__ inline float tanhfast(float x) { return 1.f - 2.f / (1.f + __expf(2.f * x)); }

__global__ __launch_bounds__(512, 2) void lstm_persistent(
    const float* __restrict__ x, const float* __restrict__ W_ih,
    const float* __restrict__ W_hh, const float* __restrict__ b_ih,
    const float* __restrict__ b_hh, float* __restrict__ out,
    int* __restrict__ flags, unsigned short* __restrict__ hbuf)
{
  __shared__ __align__(16) unsigned short v_lds[BATCH_G * VSTRIDE];   // B-operand staging
  __shared__ __align__(16) float gates_lds[ROWS_WG * GSTRIDE];
  __shared__ float bias_lds[ROWS_WG];

  const int tid  = threadIdx.x;
  const int gid  = blockIdx.x & 31;   // batch group
  const int mid  = blockIdx.x >> 5;   // member 0..7 (gate-row slice); swizzle: members share XCD
  const int wv   = tid >> 6;          // wave 0..7
  const int l    = tid & 63;
  const int l15  = l & 15, quad = l >> 4;

  // bias (b_ih + b_hh) for our 128 local gate rows: local row r -> global row (r>>5)*256 + mid*32 + (r&31)
  if (tid < ROWS_WG) {
    int grow = (tid >> 5) * H_DIM + mid * 32 + (tid & 31);
    bias_lds[tid] = b_ih[grow] + b_hh[grow];
  }

  // A-fragments: wave wv owns local rows [16*wv, 16*wv+16); lane supplies A[m=l15][k=quad*8+e]
  bf16x8 afrag[10];
  {
    int m_loc = wv * 16 + l15;
    int grow  = (m_loc >> 5) * H_DIM + mid * 32 + (m_loc & 31);
    const float* wih_row = W_ih + (long)grow * I_DIM;
    const float* whh_row = W_hh + (long)grow * H_DIM;
#pragma unroll
    for (int kt = 0; kt < 10; ++kt) {
      int kbase = kt * 32 + quad * 8;
      ushort8_t a;
#pragma unroll
      for (int e = 0; e < 8; ++e) {
        int k = kbase + e;
        float v = (k < I_DIM) ? wih_row[k] : whh_row[k - I_DIM];
        a[e] = f2bf(v);
      }
      afrag[kt] = __builtin_bit_cast(bf16x8, a);
    }
  }

  // elementwise ownership: pair p = tid + rep*512 -> jj = p&31 (h col), bb = p>>5 (batch)
  float c_reg[2] = {0.f, 0.f};
  float h_out[2] = {0.f, 0.f};

  // staging assignment: 512 threads cover 32 batch rows
  const int b_stage = tid >> 4;          // 0..31
  const int x_i4    = (tid & 15) * 4;    // 4 floats of x
  const int h_k     = (tid & 15) * 16;   // 16 bf16 of h
  const long xrow_base = ((long)(gid * 32 + b_stage)) * T_STEPS * I_DIM;

  int* gflags = flags + gid * NMEM;

  for (int t = 1; t <= T_STEPS; ++t) {
    // ---- stage x_t (fp32 -> bf16) ----
    {
      const float4 xv = *(const float4*)(x + xrow_base + (long)(t - 1) * I_DIM + x_i4);
      ushort4 xb;
      xb.x = f2bf(xv.x); xb.y = f2bf(xv.y); xb.z = f2bf(xv.z); xb.w = f2bf(xv.w);
      *(ushort4*)&v_lds[b_stage * VSTRIDE + x_i4] = xb;
    }
    // ---- h_{t-1}: poll peers, then stage ----
    if (t > 1) {
      if (tid < NMEM) {
        int target = t - 1, iter = 0;
        while (__hip_atomic_load(&gflags[tid], __ATOMIC_RELAXED, __HIP_MEMORY_SCOPE_AGENT) < target) {
          __builtin_amdgcn_s_sleep(8);
          if (++iter > (1 << 20)) break;   // safety valve vs. hang
        }
      }
      __syncthreads();
      __threadfence();  // acquire: invalidate stale cached h
      const unsigned short* hsrc =
          hbuf + ((((long)((t - 1) & 1) * NGROUP + gid) * BATCH_G + b_stage) * H_DIM) + h_k;
      uint4 h0 = *(const uint4*)(hsrc);
      uint4 h1 = *(const uint4*)(hsrc + 8);
      *(uint4*)&v_lds[b_stage * VSTRIDE + I_DIM + h_k]     = h0;
      *(uint4*)&v_lds[b_stage * VSTRIDE + I_DIM + h_k + 8] = h1;
    } else {
      uint4 z = {0, 0, 0, 0};
      *(uint4*)&v_lds[b_stage * VSTRIDE + I_DIM + h_k]     = z;
      *(uint4*)&v_lds[b_stage * VSTRIDE + I_DIM + h_k + 8] = z;
    }
    __syncthreads();

    // ---- MFMA: D[16 rows x 32 batch] per wave, K=320 ----
    f32x4 acc0 = {0.f, 0.f, 0.f, 0.f}, acc1 = {0.f, 0.f, 0.f, 0.f};
    const unsigned short* vb0 = v_lds + l15 * VSTRIDE + quad * 8;          // batch n = l15
    const unsigned short* vb1 = vb0 + 16 * VSTRIDE;                       // batch n = 16 + l15
#pragma unroll
    for (int kt = 0; kt < 10; ++kt) {
      bf16x8 b0 = __builtin_bit_cast(bf16x8, *(const uint4*)(vb0 + kt * 32));
      bf16x8 b1 = __builtin_bit_cast(bf16x8, *(const uint4*)(vb1 + kt * 32));
      acc0 = __builtin_amdgcn_mfma_f32_16x16x32_bf16(afrag[kt], b0, acc0, 0, 0, 0);
      acc1 = __builtin_amdgcn_mfma_f32_16x16x32_bf16(afrag[kt], b1, acc1, 0, 0, 0);
    }
    // D layout: row = quad*4 + r (within wave's 16), col = l15
    {
      int gr = wv * 16 + quad * 4;
#pragma unroll
      for (int r = 0; r < 4; ++r) {
        gates_lds[(gr + r) * GSTRIDE + l15]      = acc0[r];
        gates_lds[(gr + r) * GSTRIDE + 16 + l15] = acc1[r];
      }
    }
    __syncthreads();

    // ---- fused LSTM cell (c in fp32 regs) ----
#pragma unroll
    for (int rep = 0; rep < 2; ++rep) {
      int p  = tid + rep * 512;
      int jj = p & 31, bb = p >> 5;
      float gi = gates_lds[(jj)      * GSTRIDE + bb] + bias_lds[jj];
      float gf = gates_lds[(32 + jj) * GSTRIDE + bb] + bias_lds[32 + jj];
      float gg = gates_lds[(64 + jj) * GSTRIDE + bb] + bias_lds[64 + jj];
      float go = gates_lds[(96 + jj) * GSTRIDE + bb] + bias_lds[96 + jj];
      float c  = sigf(gf) * c_reg[rep] + sigf(gi) * tanhfast(gg);
      float h  = sigf(go) * tanhfast(c);
      c_reg[rep] = c; h_out[rep] = h;
      hbuf[(((long)(t & 1) * NGROUP + gid) * BATCH_G + bb) * H_DIM + mid * 32 + jj] = f2bf(h);
    }
    __syncthreads();   // all h stores drained (compiler emits vmcnt(0) before s_barrier)
    if (tid == 0) {
      __threadfence();  // release to agent scope
      __hip_atomic_store(&gflags[mid], t, __ATOMIC_RELAXED, __HIP_MEMORY_SCOPE_AGENT);
    }
  }

  // ---- outputs: h_T then c_T, fp32 (pre-bf16-rounding values) ----
#pragma unroll
  for (int rep = 0; rep < 2; ++rep) {
    int p  = tid + rep * 512;
    int jj = p & 31, bb = p >> 5;
    long o = (long)(gid * 32 + bb) * H_DIM + mid * 32 + jj;
    out[o]            = h_out[rep];
    out[OUT_HALF + o] = c_reg[rep];
  }
}

extern "C" void kernel_launch(void* const* d_in, const int* in_sizes, int n_in,
                              void* d_out, int out_size, void* d_ws, size_t ws_size,
                              hipStream_t stream) {
  const float* x    = (const float*)d_in[0];
  const float* W_ih = (const float*)d_in[1];
  const float* W_hh = (const float*)d_in[2];
  const float* b_ih = (const float*)d_in[3];
  const float* b_hh = (const float*)d_in[4];
  float* out = (float*)d_out;

  int* flags = (int*)d_ws;                                     // 32*8 ints
  unsigned short* hbuf = (unsigned short*)((char*)d_ws + 1024); // 2*32*32*256 bf16 = 1 MB

  hipMemsetAsync(d_ws, 0, 1024, stream);  // zero flags (ws is poisoned 0xAA)
  lstm_persistent<<<dim3(256), dim3(512), 0, stream>>>(x, W_ih, W_hh, b_ih, b_hh, out, flags, hbuf);
}

// Round 2
// 2141.792 us; speedup vs baseline: 6.2953x; 6.2953x over previous
//
#include <hip/hip_runtime.h>
#include <cstdint>

// LSTM: B=1024, T=336, I=64, H=256, gates 4H=1024, K = I+H = 320.
// 32 batch-groups x 8 member-WGs = 256 WGs (1/CU), persistent over all T.
// Weights live in VGPRs as MFMA A-fragments.
// h exchanged via Infinity-Cache-coherent (sc0 sc1) accesses -- NO fences,
// no L2 cache-maintenance walks (the R1 bottleneck).

#define NGROUP  32
#define NMEM    8
#define BATCH_G 32
#define ROWS_WG 128
#define T_STEPS 336
#define I_DIM   64
#define H_DIM   256
#define VSTRIDE 328   // K=320 padded (ushorts)
#define GSTRIDE 34    // 32 batch padded (floats)
#define OUT_HALF 262144  // 1024*256

typedef __attribute__((ext_vector_type(8))) __bf16 bf16x8;
typedef __attribute__((ext_vector_type(8))) unsigned short ushort8_t;
typedef __attribute__((ext_vector_type(4))) float f32x4;
typedef __attribute__((ext_vector_type(4))) unsigned uint32x4;

__device__ inline unsigned short f2bf(float f) {
  unsigned u = __builtin_bit_cast(unsigned, f);
  return (unsigned short)((u + 0x7fffu + ((u >> 16) & 1u)) >> 16);
}
__device__ inline float sigf(float x) { return 1.f / (1.f + __expf(-x)); }
__device__ inline float tanhfast(float x) { return 1.f - 2.f / (1.f + __expf(2.f * x)); }

// ---- coherent (cross-XCD) accesses: sc0 sc1 bypass per-XCD L2, served at IF ----
__device__ inline int ld_flag(const int* p) {
  int v;
  asm volatile("global_load_dword %0, %1, off sc0 sc1\n\t"
               "s_waitcnt vmcnt(0)"
               : "=v"(v) : "v"(p) : "memory");
  return v;
}
__device__ inline void ld_h32B(const unsigned short* p, uint32x4& a, uint32x4& b) {
  asm volatile("global_load_dwordx4 %0, %2, off sc0 sc1\n\t"
               "global_load_dwordx4 %1, %3, off sc0 sc1\n\t"
               "s_waitcnt vmcnt(0)"
               : "=&v"(a), "=&v"(b)
               : "v"(p), "v"(p + 8)
               : "memory");
}
__device__ inline void st_h4B(unsigned* p, unsigned v) {
  asm volatile("global_store_dword %0, %1, off sc0 sc1" :: "v"(p), "v"(v) : "memory");
}

__global__ __launch_bounds__(512, 2) void lstm_persistent(
    const float* __restrict__ x, const float* __restrict__ W_ih,
    const float* __restrict__ W_hh, const float* __restrict__ b_ih,
    const float* __restrict__ b_hh, float* __restrict__ out,
    int* __restrict__ flags, unsigned short* __restrict__ hbuf)
{
  __shared__ __align__(16) unsigned short v_lds[BATCH_G * VSTRIDE];   // B-operand staging
  __shared__ __align__(16) float gates_lds[ROWS_WG * GSTRIDE];
  __shared__ float bias_lds[ROWS_WG];

  const int tid  = threadIdx.x;
  const int gid  = blockIdx.x & 31;   // batch group
  const int mid  = blockIdx.x >> 5;   // member 0..7 (gate-row slice)
  const int wv   = tid >> 6;          // wave 0..7
  const int l    = tid & 63;
  const int l15  = l & 15, quad = l >> 4;

  // bias (b_ih + b_hh) for our 128 local gate rows: local row r -> global row (r>>5)*256 + mid*32 + (r&31)
  if (tid < ROWS_WG) {
    int grow = (tid >> 5) * H_DIM + mid * 32 + (tid & 31);
    bias_lds[tid] = b_ih[grow] + b_hh[grow];
  }

  // A-fragments: wave wv owns local rows [16*wv, 16*wv+16); lane supplies A[m=l15][k=quad*8+e]
  bf16x8 afrag[10];
  {
    int m_loc = wv * 16 + l15;
    int grow  = (m_loc >> 5) * H_DIM + mid * 32 + (m_loc & 31);
    const float* wih_row = W_ih + (long)grow * I_DIM;
    const float* whh_row = W_hh + (long)grow * H_DIM;
#pragma unroll
    for (int kt = 0; kt < 10; ++kt) {
      int kbase = kt * 32 + quad * 8;
      ushort8_t a;
#pragma unroll
      for (int e = 0; e < 8; ++e) {
        int k = kbase + e;
        float v = (k < I_DIM) ? wih_row[k] : whh_row[k - I_DIM];
        a[e] = f2bf(v);
      }
      afrag[kt] = __builtin_bit_cast(bf16x8, a);
    }
  }

  // cell ownership: thread -> batch bb = tid>>4, column pair jj = 2*(tid&15), 2*(tid&15)+1
  const int bb = tid >> 4;
  const int jp = tid & 15;
  const int jj = jp * 2;
  float c_reg[2] = {0.f, 0.f};
  float h_out[2] = {0.f, 0.f};

  // staging assignment: 512 threads cover 32 batch rows
  const int b_stage = tid >> 4;          // 0..31
  const int x_i4    = (tid & 15) * 4;    // 4 floats of x
  const int h_k     = (tid & 15) * 16;   // 16 bf16 of h
  const long xrow_base = ((long)(gid * 32 + b_stage)) * T_STEPS * I_DIM;

  int* gflags = flags + gid * NMEM;
  const int* pollp = gflags + ((tid & 15) >> 1);  // the one member this thread stages from
  unsigned* hbuf32 = (unsigned*)hbuf;

  for (int t = 1; t <= T_STEPS; ++t) {
    // ---- issue x_t load early (overlaps the poll) ----
    const float4 xv = *(const float4*)(x + xrow_base + (long)(t - 1) * I_DIM + x_i4);

    // ---- poll: wait for the member whose h-slice this thread stages ----
    if (t > 1) {
      const int target = 8 * (t - 1);   // 8 waves per member increment the flag each step
      int it = 0;
      while (ld_flag(pollp) < target) {
        if (++it > (1 << 16)) break;    // safety valve vs. hang
      }
    }

    // ---- stage x_t (fp32 -> bf16) ----
    {
      ushort4 xb;
      xb.x = f2bf(xv.x); xb.y = f2bf(xv.y); xb.z = f2bf(xv.z); xb.w = f2bf(xv.w);
      *(ushort4*)&v_lds[b_stage * VSTRIDE + x_i4] = xb;
    }
    // ---- stage h_{t-1} via coherent loads ----
    if (t > 1) {
      const unsigned short* hsrc =
          hbuf + ((((long)((t - 1) & 1) * NGROUP + gid) * BATCH_G + b_stage) * H_DIM) + h_k;
      uint32x4 h0, h1;
      ld_h32B(hsrc, h0, h1);
      *(uint32x4*)&v_lds[b_stage * VSTRIDE + I_DIM + h_k]     = h0;
      *(uint32x4*)&v_lds[b_stage * VSTRIDE + I_DIM + h_k + 8] = h1;
    } else {
      uint32x4 z = {0, 0, 0, 0};
      *(uint32x4*)&v_lds[b_stage * VSTRIDE + I_DIM + h_k]     = z;
      *(uint32x4*)&v_lds[b_stage * VSTRIDE + I_DIM + h_k + 8] = z;
    }
    __syncthreads();   // barrier 1: staging complete

    // ---- MFMA: D[16 rows x 32 batch] per wave, K=320 ----
    f32x4 acc0 = {0.f, 0.f, 0.f, 0.f}, acc1 = {0.f, 0.f, 0.f, 0.f};
    const unsigned short* vb0 = v_lds + l15 * VSTRIDE + quad * 8;   // batch n = l15
    const unsigned short* vb1 = vb0 + 16 * VSTRIDE;                 // batch n = 16 + l15
#pragma unroll
    for (int kt = 0; kt < 10; ++kt) {
      bf16x8 b0 = __builtin_bit_cast(bf16x8, *(const uint32x4*)(vb0 + kt * 32));
      bf16x8 b1 = __builtin_bit_cast(bf16x8, *(const uint32x4*)(vb1 + kt * 32));
      acc0 = __builtin_amdgcn_mfma_f32_16x16x32_bf16(afrag[kt], b0, acc0, 0, 0, 0);
      acc1 = __builtin_amdgcn_mfma_f32_16x16x32_bf16(afrag[kt], b1, acc1, 0, 0, 0);
    }
    // D layout: row = quad*4 + r (within wave's 16 local rows), col = l15
    {
      int gr = wv * 16 + quad * 4;
#pragma unroll
      for (int r = 0; r < 4; ++r) {
        gates_lds[(gr + r) * GSTRIDE + l15]      = acc0[r];
        gates_lds[(gr + r) * GSTRIDE + 16 + l15] = acc1[r];
      }
    }
    __syncthreads();   // barrier 2: gates ready

    // ---- fused LSTM cell (c in fp32 regs), 2 adjacent columns per thread ----
    {
      float gi0 = gates_lds[(jj)          * GSTRIDE + bb] + bias_lds[jj];
      float gf0 = gates_lds[(32 + jj)     * GSTRIDE + bb] + bias_lds[32 + jj];
      float gg0 = gates_lds[(64 + jj)     * GSTRIDE + bb] + bias_lds[64 + jj];
      float go0 = gates_lds[(96 + jj)     * GSTRIDE + bb] + bias_lds[96 + jj];
      float gi1 = gates_lds[(jj + 1)      * GSTRIDE + bb] + bias_lds[jj + 1];
      float gf1 = gates_lds[(32 + jj + 1) * GSTRIDE + bb] + bias_lds[32 + jj + 1];
      float gg1 = gates_lds[(64 + jj + 1) * GSTRIDE + bb] + bias_lds[64 + jj + 1];
      float go1 = gates_lds[(96 + jj + 1) * GSTRIDE + bb] + bias_lds[96 + jj + 1];
      float c0 = sigf(gf0) * c_reg[0] + sigf(gi0) * tanhfast(gg0);
      float c1 = sigf(gf1) * c_reg[1] + sigf(gi1) * tanhfast(gg1);
      float h0 = sigf(go0) * tanhfast(c0);
      float h1 = sigf(go1) * tanhfast(c1);
      c_reg[0] = c0; c_reg[1] = c1; h_out[0] = h0; h_out[1] = h1;
      unsigned pack = (unsigned)f2bf(h0) | ((unsigned)f2bf(h1) << 16);
      unsigned* dst = hbuf32 +
          ((((long)(t & 1) * NGROUP + gid) * BATCH_G + bb) * (H_DIM / 2)) + mid * 16 + jp;
      st_h4B(dst, pack);
    }
    // ---- per-wave: drain stores to coherence point, then bump flag ----
    asm volatile("s_waitcnt vmcnt(0)" ::: "memory");
    if (l == 0) {
      __hip_atomic_fetch_add(&gflags[mid], 1, __ATOMIC_RELAXED, __HIP_MEMORY_SCOPE_AGENT);
    }
  }

  // ---- outputs: h_T then c_T, fp32 (pre-bf16-rounding values) ----
  {
    long o = (long)(gid * 32 + bb) * H_DIM + mid * 32 + jj;
    float2 hv; hv.x = h_out[0]; hv.y = h_out[1];
    float2 cv; cv.x = c_reg[0]; cv.y = c_reg[1];
    *(float2*)&out[o]            = hv;
    *(float2*)&out[OUT_HALF + o] = cv;
  }
}

extern "C" void kernel_launch(void* const* d_in, const int* in_sizes, int n_in,
                              void* d_out, int out_size, void* d_ws, size_t ws_size,
                              hipStream_t stream) {
  const float* x    = (const float*)d_in[0];
  const float* W_ih = (const float*)d_in[1];
  const float* W_hh = (const float*)d_in[2];
  const float* b_ih = (const float*)d_in[3];
  const float* b_hh = (const float*)d_in[4];
  float* out = (float*)d_out;

  int* flags = (int*)d_ws;                                      // 32*8 ints
  unsigned short* hbuf = (unsigned short*)((char*)d_ws + 1024); // 2*32*32*256 bf16 = 1 MB

  hipMemsetAsync(d_ws, 0, 1024, stream);  // zero flags (ws is poisoned 0xAA)
  lstm_persistent<<<dim3(256), dim3(512), 0, stream>>>(x, W_ih, W_hh, b_ih, b_hh, out, flags, hbuf);
}

// Round 3
// 1088.915 us; speedup vs baseline: 12.3822x; 1.9669x over previous
//
#include <hip/hip_runtime.h>
#include <cstdint>

// LSTM: B=1024, T=336, I=64, H=256, gates 4H=1024, K = I+H = 320.
// 32 batch-groups x 8 member-WGs = 256 WGs (1/CU), persistent over all T.
// Weights live in VGPRs as MFMA A-fragments.
// R3: h exchanged as (tag,data) 8-byte pairs via IF-coherent (sc0 sc1)
// accesses. No flags, no atomics, no producer drain: consumer polls the
// data itself and accepts when tag == step. Single aligned 8B stores
// cannot tear, so tag-valid => data-valid.

#define NGROUP  32
#define NMEM    8
#define BATCH_G 32
#define ROWS_WG 128
#define T_STEPS 336
#define I_DIM   64
#define H_DIM   256
#define VSTRIDE 328   // K=320 padded (ushorts)
#define GSTRIDE 34    // 32 batch padded (floats)
#define OUT_HALF 262144  // 1024*256
#define PAIRS   128      // h-pairs per batch row (256 cols / 2)

typedef __attribute__((ext_vector_type(8))) __bf16 bf16x8;
typedef __attribute__((ext_vector_type(8))) unsigned short ushort8_t;
typedef __attribute__((ext_vector_type(4))) float f32x4;
typedef __attribute__((ext_vector_type(4))) unsigned uint32x4;
typedef __attribute__((ext_vector_type(2))) unsigned uint32x2;

__device__ inline unsigned short f2bf(float f) {
  unsigned u = __builtin_bit_cast(unsigned, f);
  return (unsigned short)((u + 0x7fffu + ((u >> 16) & 1u)) >> 16);
}
__device__ inline float sigf(float x) { return 1.f / (1.f + __expf(-x)); }
__device__ inline float tanhfast(float x) { return 1.f - 2.f / (1.f + __expf(2.f * x)); }

// 4 concurrent coherent 16B loads (8 tagged pairs), one round trip.
__device__ inline void ld4_tagged(const uint32x2* p, uint32x4& a, uint32x4& b,
                                  uint32x4& c, uint32x4& d) {
  asm volatile(
      "global_load_dwordx4 %0, %4, off sc0 sc1\n\t"
      "global_load_dwordx4 %1, %5, off sc0 sc1\n\t"
      "global_load_dwordx4 %2, %6, off sc0 sc1\n\t"
      "global_load_dwordx4 %3, %7, off sc0 sc1\n\t"
      "s_waitcnt vmcnt(0)"
      : "=&v"(a), "=&v"(b), "=&v"(c), "=&v"(d)
      : "v"(p), "v"(p + 2), "v"(p + 4), "v"(p + 6)
      : "memory");
}
__device__ inline void st_pair(uint32x2* p, uint32x2 v) {
  asm volatile("global_store_dwordx2 %0, %1, off sc0 sc1" :: "v"(p), "v"(v) : "memory");
}

__global__ __launch_bounds__(512, 2) void lstm_persistent(
    const float* __restrict__ x, const float* __restrict__ W_ih,
    const float* __restrict__ W_hh, const float* __restrict__ b_ih,
    const float* __restrict__ b_hh, float* __restrict__ out,
    uint32x2* __restrict__ hbuf)
{
  __shared__ __align__(16) unsigned short v_lds[BATCH_G * VSTRIDE];   // B-operand staging
  __shared__ __align__(16) float gates_lds[ROWS_WG * GSTRIDE];
  __shared__ float bias_lds[ROWS_WG];

  const int tid  = threadIdx.x;
  const int gid  = blockIdx.x & 31;   // batch group
  const int mid  = blockIdx.x >> 5;   // member 0..7 (gate-row slice)
  const int wv   = tid >> 6;          // wave 0..7
  const int l    = tid & 63;
  const int l15  = l & 15, quad = l >> 4;

  // bias (b_ih + b_hh) for our 128 local gate rows
  if (tid < ROWS_WG) {
    int grow = (tid >> 5) * H_DIM + mid * 32 + (tid & 31);
    bias_lds[tid] = b_ih[grow] + b_hh[grow];
  }

  // A-fragments: wave wv owns local rows [16*wv, 16*wv+16); lane supplies A[m=l15][k=quad*8+e]
  bf16x8 afrag[10];
  {
    int m_loc = wv * 16 + l15;
    int grow  = (m_loc >> 5) * H_DIM + mid * 32 + (m_loc & 31);
    const float* wih_row = W_ih + (long)grow * I_DIM;
    const float* whh_row = W_hh + (long)grow * H_DIM;
#pragma unroll
    for (int kt = 0; kt < 10; ++kt) {
      int kbase = kt * 32 + quad * 8;
      ushort8_t a;
#pragma unroll
      for (int e = 0; e < 8; ++e) {
        int k = kbase + e;
        float v = (k < I_DIM) ? wih_row[k] : whh_row[k - I_DIM];
        a[e] = f2bf(v);
      }
      afrag[kt] = __builtin_bit_cast(bf16x8, a);
    }
  }

  // cell ownership: thread -> batch bb = tid>>4, column pair jp = tid&15 (cols jj, jj+1)
  const int bb = tid >> 4;
  const int jp = tid & 15;
  const int jj = jp * 2;
  float c_reg[2] = {0.f, 0.f};
  float h_out[2] = {0.f, 0.f};

  // staging assignment: 512 threads cover 32 batch rows; 16 threads/row, 8 pairs each
  const int b_stage = tid >> 4;          // 0..31
  const int x_i4    = (tid & 15) * 4;    // 4 floats of x
  const int h_k     = (tid & 15) * 16;   // 16 bf16 of h (= pairs pi_base..pi_base+7)
  const int pi_base = (tid & 15) * 8;
  const long xrow_base = ((long)(gid * 32 + b_stage)) * T_STEPS * I_DIM;

  uint32x2* st_dst_base = hbuf + ((long)gid * BATCH_G + bb) * PAIRS + mid * 16 + jp;
  const uint32x2* ld_src_base = hbuf + ((long)gid * BATCH_G + b_stage) * PAIRS + pi_base;
  const long buf_stride = (long)NGROUP * BATCH_G * PAIRS;   // pairs per buffer

  for (int t = 1; t <= T_STEPS; ++t) {
    // ---- issue x_t load early (overlaps the poll) ----
    const float4 xv = *(const float4*)(x + xrow_base + (long)(t - 1) * I_DIM + x_i4);

    // ---- stage x_t (fp32 -> bf16) ----
    {
      ushort4 xb;
      xb.x = f2bf(xv.x); xb.y = f2bf(xv.y); xb.z = f2bf(xv.z); xb.w = f2bf(xv.w);
      *(ushort4*)&v_lds[b_stage * VSTRIDE + x_i4] = xb;
    }

    // ---- stage h_{t-1}: poll the tagged data directly ----
    if (t > 1) {
      const unsigned tag = (unsigned)(t - 1);
      const uint32x2* hsrc = ld_src_base + ((t - 1) & 1) * buf_stride;
      uint32x4 A, Bv, C, D;
      int it = 0;
      for (;;) {
        ld4_tagged(hsrc, A, Bv, C, D);
        bool ok = (A[0] == tag) & (A[2] == tag) & (Bv[0] == tag) & (Bv[2] == tag) &
                  (C[0] == tag) & (C[2] == tag) & (D[0] == tag) & (D[2] == tag);
        if (ok) break;
        if (++it > (1 << 17)) break;   // safety valve vs. hang
        __builtin_amdgcn_s_sleep(1);
      }
      uint32x4 e0, e1;
      e0[0] = A[1]; e0[1] = A[3]; e0[2] = Bv[1]; e0[3] = Bv[3];
      e1[0] = C[1]; e1[1] = C[3]; e1[2] = D[1];  e1[3] = D[3];
      *(uint32x4*)&v_lds[b_stage * VSTRIDE + I_DIM + h_k]     = e0;
      *(uint32x4*)&v_lds[b_stage * VSTRIDE + I_DIM + h_k + 8] = e1;
    } else {
      uint32x4 z = {0, 0, 0, 0};
      *(uint32x4*)&v_lds[b_stage * VSTRIDE + I_DIM + h_k]     = z;
      *(uint32x4*)&v_lds[b_stage * VSTRIDE + I_DIM + h_k + 8] = z;
    }
    __syncthreads();   // barrier 1: staging complete

    // ---- MFMA: D[16 rows x 32 batch] per wave, K=320 ----
    f32x4 acc0 = {0.f, 0.f, 0.f, 0.f}, acc1 = {0.f, 0.f, 0.f, 0.f};
    const unsigned short* vb0 = v_lds + l15 * VSTRIDE + quad * 8;   // batch n = l15
    const unsigned short* vb1 = vb0 + 16 * VSTRIDE;                 // batch n = 16 + l15
#pragma unroll
    for (int kt = 0; kt < 10; ++kt) {
      bf16x8 b0 = __builtin_bit_cast(bf16x8, *(const uint32x4*)(vb0 + kt * 32));
      bf16x8 b1 = __builtin_bit_cast(bf16x8, *(const uint32x4*)(vb1 + kt * 32));
      acc0 = __builtin_amdgcn_mfma_f32_16x16x32_bf16(afrag[kt], b0, acc0, 0, 0, 0);
      acc1 = __builtin_amdgcn_mfma_f32_16x16x32_bf16(afrag[kt], b1, acc1, 0, 0, 0);
    }
    // D layout: row = quad*4 + r (within wave's 16 local rows), col = l15
    {
      int gr = wv * 16 + quad * 4;
#pragma unroll
      for (int r = 0; r < 4; ++r) {
        gates_lds[(gr + r) * GSTRIDE + l15]      = acc0[r];
        gates_lds[(gr + r) * GSTRIDE + 16 + l15] = acc1[r];
      }
    }
    __syncthreads();   // barrier 2: gates ready

    // ---- fused LSTM cell (c in fp32 regs), 2 adjacent columns per thread ----
    {
      float gi0 = gates_lds[(jj)          * GSTRIDE + bb] + bias_lds[jj];
      float gf0 = gates_lds[(32 + jj)     * GSTRIDE + bb] + bias_lds[32 + jj];
      float gg0 = gates_lds[(64 + jj)     * GSTRIDE + bb] + bias_lds[64 + jj];
      float go0 = gates_lds[(96 + jj)     * GSTRIDE + bb] + bias_lds[96 + jj];
      float gi1 = gates_lds[(jj + 1)      * GSTRIDE + bb] + bias_lds[jj + 1];
      float gf1 = gates_lds[(32 + jj + 1) * GSTRIDE + bb] + bias_lds[32 + jj + 1];
      float gg1 = gates_lds[(64 + jj + 1) * GSTRIDE + bb] + bias_lds[64 + jj + 1];
      float go1 = gates_lds[(96 + jj + 1) * GSTRIDE + bb] + bias_lds[96 + jj + 1];
      float c0 = sigf(gf0) * c_reg[0] + sigf(gi0) * tanhfast(gg0);
      float c1 = sigf(gf1) * c_reg[1] + sigf(gi1) * tanhfast(gg1);
      float h0 = sigf(go0) * tanhfast(c0);
      float h1 = sigf(go1) * tanhfast(c1);
      c_reg[0] = c0; c_reg[1] = c1; h_out[0] = h0; h_out[1] = h1;
      uint32x2 pv;
      pv[0] = (unsigned)t;                                        // tag
      pv[1] = (unsigned)f2bf(h0) | ((unsigned)f2bf(h1) << 16);    // data
      st_pair(st_dst_base + (t & 1) * buf_stride, pv);            // fire-and-forget
    }
    // no drain, no flag: next iteration's poll validates the data itself
  }

  // ---- outputs: h_T then c_T, fp32 (pre-bf16-rounding values) ----
  {
    long o = (long)(gid * 32 + bb) * H_DIM + mid * 32 + jj;
    float2 hv; hv.x = h_out[0]; hv.y = h_out[1];
    float2 cv; cv.x = c_reg[0]; cv.y = c_reg[1];
    *(float2*)&out[o]            = hv;
    *(float2*)&out[OUT_HALF + o] = cv;
  }
}

extern "C" void kernel_launch(void* const* d_in, const int* in_sizes, int n_in,
                              void* d_out, int out_size, void* d_ws, size_t ws_size,
                              hipStream_t stream) {
  const float* x    = (const float*)d_in[0];
  const float* W_ih = (const float*)d_in[1];
  const float* W_hh = (const float*)d_in[2];
  const float* b_ih = (const float*)d_in[3];
  const float* b_hh = (const float*)d_in[4];
  float* out = (float*)d_out;

  uint32x2* hbuf = (uint32x2*)d_ws;   // 2 buffers x 32x32x128 pairs x 8 B = 2 MB

  // Clear tags so no stale value can match t in [1,336] (poison 0xAA also
  // can't match, but zeroing makes correctness independent of the harness).
  hipMemsetAsync(d_ws, 0, 2u * NGROUP * BATCH_G * PAIRS * 8u, stream);
  lstm_persistent<<<dim3(256), dim3(512), 0, stream>>>(x, W_ih, W_hh, b_ih, b_hh, out, hbuf);
}